// Round 3
// baseline (270.572 us; speedup 1.0000x reference)
//
#include <hip/hip_runtime.h>

#define S_LEN 4096
#define DHEAD 64
#define BK    64       // K/V rows per tile
#define NT    (S_LEN / BK)
#define NBH   16
#define KPAD  72       // fallback kernel only
#define BQ    128      // fallback kernel only
#define TILE_HALFS (BK * DHEAD)   // 4096 halfs = 8 KB per tile image
#define WS_KV_HALFS ((size_t)NBH * NT * TILE_HALFS)

typedef __fp16   pk16x2 __attribute__((ext_vector_type(2)));
typedef _Float16 half4v __attribute__((ext_vector_type(4)));
typedef _Float16 half8  __attribute__((ext_vector_type(8)));
typedef float    f32x4  __attribute__((ext_vector_type(4)));
typedef float    f32x16 __attribute__((ext_vector_type(16)));
typedef unsigned uint2v __attribute__((ext_vector_type(2)));

#define MFMA32(a, b, c) __builtin_amdgcn_mfma_f32_32x32x16_f16(a, b, c, 0, 0, 0)

__device__ __forceinline__ void gl_lds16(const _Float16* g, _Float16* l) {
    __builtin_amdgcn_global_load_lds(
        (const __attribute__((address_space(1))) unsigned int*)g,
        (__attribute__((address_space(3))) unsigned int*)l, 16, 0, 0);
}

__device__ __forceinline__ unsigned pk2u(float a, float b) {
    union { pk16x2 p; unsigned u; } x;
    x.p = __builtin_amdgcn_cvt_pkrtz(a, b);
    return x.u;
}

// permlane32_swap(x,x): r.x = value of lane (l&31), r.y = value of lane (l&31)+32
__device__ __forceinline__ uint2v pls(unsigned x, unsigned y) {
    return __builtin_amdgcn_permlane32_swap(x, y, false, false);
}
__device__ __forceinline__ float xmax32(float v) {
    uint2v r = pls(__float_as_uint(v), __float_as_uint(v));
    return fmaxf(__uint_as_float(r.x), __uint_as_float(r.y));
}
__device__ __forceinline__ float xadd32(float v) {
    uint2v r = pls(__float_as_uint(v), __float_as_uint(v));
    return __uint_as_float(r.x) + __uint_as_float(r.y);
}

// ---------------------------------------------------------------------------
// Mask scan (fallback path)
// ---------------------------------------------------------------------------
__global__ void mask_flag_kernel(const float4* __restrict__ mask, int* __restrict__ flag) {
    const long stride = 2048L * 256;
    long i = (long)blockIdx.x * 256 + threadIdx.x;
    int nz = 0;
    #pragma unroll
    for (int it = 0; it < 8; ++it) {
        float4 a = mask[i + it * stride];
        nz |= (a.x != 0.f) | (a.y != 0.f) | (a.z != 0.f) | (a.w != 0.f);
    }
    if (__any(nz)) {
        if ((threadIdx.x & 63) == 0) atomicOr(flag, 1);
    }
}

// ---------------------------------------------------------------------------
// Convert K/V fp32 -> fp16 swizzled tile images + mask scan (unchanged layout:
//   wsK: [r][chunk c] = K[r][8*(c^(r&7))..+8]; wsV: [d][c] = V[8*(c^(d&7))..][d])
// ---------------------------------------------------------------------------
__global__ void conv_kernel(const float* __restrict__ Kg, const float* __restrict__ Vg,
                            const float* __restrict__ mask,
                            _Float16* __restrict__ wsK, _Float16* __restrict__ wsV,
                            int* __restrict__ flag) {
    const int tid  = threadIdx.x;
    const int tile = blockIdx.x;
    __shared__ __align__(16) _Float16 T[64][64];

    if (blockIdx.y == 0) {
        const float* Ksrc = Kg + (long)tile * TILE_HALFS;
        _Float16*    dst  = wsK + (long)tile * TILE_HALFS;
        #pragma unroll
        for (int it = 0; it < 2; ++it) {
            int m = tid + it * 256;
            int r = m >> 3, c = m & 7;
            const float4* s4 = (const float4*)(Ksrc + r * DHEAD + ((c ^ (r & 7)) << 3));
            float4 a = s4[0], b = s4[1];
            union { pk16x2 p[4]; half8 h; } u;
            u.p[0] = __builtin_amdgcn_cvt_pkrtz(a.x, a.y);
            u.p[1] = __builtin_amdgcn_cvt_pkrtz(a.z, a.w);
            u.p[2] = __builtin_amdgcn_cvt_pkrtz(b.x, b.y);
            u.p[3] = __builtin_amdgcn_cvt_pkrtz(b.z, b.w);
            *(half8*)(dst + m * 8) = u.h;
        }
    } else if (blockIdx.y == 1) {
        const float* Vsrc = Vg + (long)tile * TILE_HALFS;
        const int r  = tid >> 2;
        const int d0 = (tid & 3) << 4;
        const float4* s4 = (const float4*)(Vsrc + r * DHEAD + d0);
        float vv[16];
        *(float4*)&vv[0]  = s4[0];
        *(float4*)&vv[4]  = s4[1];
        *(float4*)&vv[8]  = s4[2];
        *(float4*)&vv[12] = s4[3];
        #pragma unroll
        for (int j = 0; j < 16; j += 2) {
            pk16x2 p = __builtin_amdgcn_cvt_pkrtz(vv[j], vv[j + 1]);
            T[d0 + j][r]     = *((_Float16*)&p);
            T[d0 + j + 1][r] = *((_Float16*)&p + 1);
        }
        __syncthreads();
        _Float16* dst = wsV + (long)tile * TILE_HALFS;
        #pragma unroll
        for (int it = 0; it < 2; ++it) {
            int m = tid + it * 256;
            int d = m >> 3, c = m & 7;
            *(half8*)(dst + m * 8) = *(const half8*)&T[d][(c ^ (d & 7)) << 3];
        }
    } else {
        const float4* m4 = (const float4*)mask;
        const long stride = 1024L * 256;
        long i = (long)blockIdx.x * 256 + tid;
        int nz = 0;
        #pragma unroll
        for (int it = 0; it < 16; ++it) {
            float4 a = m4[i + it * stride];
            nz |= (a.x != 0.f) | (a.y != 0.f) | (a.z != 0.f) | (a.w != 0.f);
        }
        if (__any(nz)) {
            if ((tid & 63) == 0) atomicOr(flag, 1);
        }
    }
}

// ---------------------------------------------------------------------------
// Flash attention, 32x32x16 MFMA, 4 waves x 32 q-rows (BQ=128), KV-split.
// S^T = K.Q^T in 32x32 layout: each lane owns ONE q-column -> softmax reduce
// is 31 fmax + 1 permlane32_swap (no DS). P redistributed to the PV A-operand
// entirely in-register (cvt_pkrtz + permlane32_swap + cndmask) -> no P LDS.
// LDS = KT+VT dbuf = 32 KB -> 4 blocks/CU at grid 1024 (SPLIT=2).
// ---------------------------------------------------------------------------
template <int SPLIT>
__global__ __launch_bounds__(256, 4) void attn32_kernel(
    const float* __restrict__ Q, const _Float16* __restrict__ KW,
    const _Float16* __restrict__ VW, const int* __restrict__ dkp,
    const float* __restrict__ mask, const int* __restrict__ maskflag,
    float* __restrict__ O1, float* __restrict__ O2, float* __restrict__ ML)
{
    // XCD-aware decode: consecutive logical ids (same bh) land on same XCD.
    const int fid = blockIdx.x;
    int bh, half, qt;
    if (SPLIT == 2) {
        const int L = (fid & 7) * 128 + (fid >> 3);   // 1024 blocks
        bh = L >> 6; half = (L >> 5) & 1; qt = L & 31;
    } else {
        const int L = (fid & 7) * 64 + (fid >> 3);    // 512 blocks
        bh = L >> 5; half = 0; qt = L & 31;
    }
    const int HT  = NT / SPLIT;
    const int kt0 = half * HT;

    const int tid  = threadIdx.x;
    const int wave = tid >> 6;
    const int lane = tid & 63;
    const int l31  = lane & 31;
    const int h    = lane >> 5;          // lane half
    const int cx   = lane & 7;           // chunk-XOR key
    const bool hib = (lane >= 32);

    const long base = (long)bh * S_LEN * DHEAD;
    const float* Qh = Q + base;
    const _Float16* gk = KW + (long)bh * (NT * TILE_HALFS);
    const _Float16* gv = VW + (long)bh * (NT * TILE_HALFS);

    const int q0 = qt * 128 + wave * 32;
    const float csq  = rsqrtf((float)dkp[0]) * 1.44269504088896f;
    const float mfac = -1e9f * 1.44269504088896f;
    const bool use_mask = (maskflag[0] != 0);

    __shared__ __align__(16) _Float16 KT[2][TILE_HALFS];   // 16 KB
    __shared__ __align__(16) _Float16 VT[2][TILE_HALFS];   // 16 KB

    // Q B-operand frags: lane -> Q[q0+l31][ks*16 + 8h + j], pre-scaled
    half8 qf[4];
    #pragma unroll
    for (int ks = 0; ks < 4; ++ks) {
        const float4* src = (const float4*)(Qh + (long)(q0 + l31) * DHEAD + ks * 16 + h * 8);
        float4 a = src[0], b = src[1];
        union { unsigned u[4]; half8 h8; } u;
        u.u[0] = pk2u(a.x * csq, a.y * csq);
        u.u[1] = pk2u(a.z * csq, a.w * csq);
        u.u[2] = pk2u(b.x * csq, b.y * csq);
        u.u[3] = pk2u(b.z * csq, b.w * csq);
        qf[ks] = u.h8;
    }

    auto stage = [&](int kt, int bb) {
        const _Float16* k8 = gk + (long)kt * TILE_HALFS + tid * 8;
        const _Float16* v8 = gv + (long)kt * TILE_HALFS + tid * 8;
        gl_lds16(k8,        &KT[bb][tid * 8]);
        gl_lds16(k8 + 2048, &KT[bb][2048 + tid * 8]);
        gl_lds16(v8,        &VT[bb][tid * 8]);
        gl_lds16(v8 + 2048, &VT[bb][2048 + tid * 8]);
    };

    f32x16 o0 = {0.f,0.f,0.f,0.f,0.f,0.f,0.f,0.f,0.f,0.f,0.f,0.f,0.f,0.f,0.f,0.f};
    f32x16 o1 = o0;
    float m_i = -INFINITY;
    float l_i = 0.0f;

    stage(kt0, 0);
    __syncthreads();

    for (int lt = 0; lt < HT; ++lt) {
        const int kt = kt0 + lt;
        const int b  = lt & 1;
        if (lt + 1 < HT) stage(kt + 1, b ^ 1);

        // ---- S^T = K . Q^T : st[kb] covers k-rows kb*32..+32 x 32 q ----
        f32x16 s0 = {0.f,0.f,0.f,0.f,0.f,0.f,0.f,0.f,0.f,0.f,0.f,0.f,0.f,0.f,0.f,0.f};
        f32x16 s1 = s0;
        __builtin_amdgcn_s_setprio(1);
        #pragma unroll
        for (int ks = 0; ks < 4; ++ks) {
            const int off = (((2 * ks + h) ^ cx) << 3);
            half8 a0 = *(const half8*)&KT[b][(l31 << 6) + off];
            half8 a1 = *(const half8*)&KT[b][2048 + (l31 << 6) + off];
            s0 = MFMA32(a0, qf[ks], s0);
            s1 = MFMA32(a1, qf[ks], s1);
        }
        __builtin_amdgcn_s_setprio(0);

        if (use_mask) {
            const float* mrow = mask + (long)(q0 + l31) * S_LEN + kt * BK;
            #pragma unroll
            for (int r = 0; r < 16; ++r) {
                const int k = (r & 3) + ((r >> 2) << 3) + (h << 2);
                s0[r] += mfac * mrow[k];
                s1[r] += mfac * mrow[32 + k];
            }
        }

        // ---- online softmax; lane owns q = l31 (dup across halves) ----
        {
            float t[8];
            #pragma unroll
            for (int i = 0; i < 8; ++i)
                t[i] = fmaxf(fmaxf(s0[2*i], s0[2*i+1]), fmaxf(s1[2*i], s1[2*i+1]));
            float mx = fmaxf(fmaxf(fmaxf(t[0], t[1]), fmaxf(t[2], t[3])),
                             fmaxf(fmaxf(t[4], t[5]), fmaxf(t[6], t[7])));
            mx = xmax32(mx);
            const bool need = __any(mx > m_i);
            const float mnew = need ? fmaxf(m_i, mx) : m_i;
            float ra = 0.f, rb = 0.f;
            #pragma unroll
            for (int r = 0; r < 16; ++r) {
                float p0 = __builtin_amdgcn_exp2f(s0[r] - mnew);
                float p1 = __builtin_amdgcn_exp2f(s1[r] - mnew);
                s0[r] = p0; s1[r] = p1;
                ra += p0; rb += p1;
            }
            float rsum = xadd32(ra + rb);
            if (need) {
                const float alpha = __builtin_amdgcn_exp2f(m_i - mnew);
                #pragma unroll
                for (int r = 0; r < 16; ++r) {
                    const int qr = (r & 3) + ((r >> 2) << 3) + (h << 2);
                    float a_r = __shfl(alpha, qr, 64);
                    o0[r] *= a_r; o1[r] *= a_r;
                }
                l_i = alpha * l_i + rsum;
                m_i = mnew;
            } else {
                l_i += rsum;
            }
        }

        // ---- P -> PV A-operand, fully in-register ----
        // plo[kb*8+d] = pk(s[2d],s[2d+1]) of lane l31 ; phi: of lane l31+32
        unsigned plo[16], phi[16];
        #pragma unroll
        for (int d = 0; d < 8; ++d) {
            uint2v r0 = pls(pk2u(s0[2*d], s0[2*d+1]), pk2u(s0[2*d], s0[2*d+1]));
            plo[d] = r0.x; phi[d] = r0.y;
            uint2v r1 = pls(pk2u(s1[2*d], s1[2*d+1]), pk2u(s1[2*d], s1[2*d+1]));
            plo[8 + d] = r1.x; phi[8 + d] = r1.y;
        }

        // ---- O += P.V ----
        __builtin_amdgcn_s_setprio(1);
        #pragma unroll
        for (int s = 0; s < 4; ++s) {
            const int kb = s >> 1, tq = s & 1, bs = kb * 8 + 4 * tq;
            union { unsigned u[4]; half8 h8; } pa;
            pa.u[0] = hib ? plo[bs + 2] : plo[bs + 0];
            pa.u[1] = hib ? plo[bs + 3] : plo[bs + 1];
            pa.u[2] = hib ? phi[bs + 2] : phi[bs + 0];
            pa.u[3] = hib ? phi[bs + 3] : phi[bs + 1];
            const int off = (((2 * s + h) ^ cx) << 3);
            half8 v0 = *(const half8*)&VT[b][(l31 << 6) + off];
            half8 v1 = *(const half8*)&VT[b][2048 + (l31 << 6) + off];
            o0 = MFMA32(pa.h8, v0, o0);
            o1 = MFMA32(pa.h8, v1, o1);
        }
        __builtin_amdgcn_s_setprio(0);

        if (lt + 1 < HT) __syncthreads();
    }

    // ---- epilogue ----
    if (SPLIT == 2) {
        float* dst = ((half == 0) ? O1 : O2) + base;
        #pragma unroll
        for (int r = 0; r < 16; ++r) {
            const int qr = (r & 3) + ((r >> 2) << 3) + (h << 2);
            const long row = (long)(q0 + qr) * DHEAD;
            dst[row + l31]      = o0[r];
            dst[row + 32 + l31] = o1[r];
        }
        if (!hib) {
            float2* ml = (float2*)ML + (long)(half * NBH + bh) * S_LEN + q0 + l31;
            *ml = make_float2(m_i, l_i);
        }
    } else {
        float* dst = O1 + base;
        #pragma unroll
        for (int r = 0; r < 16; ++r) {
            const int qr = (r & 3) + ((r >> 2) << 3) + (h << 2);
            float lq = __shfl(l_i, qr, 64);
            float inv = __builtin_amdgcn_rcpf(lq);
            const long row = (long)(q0 + qr) * DHEAD;
            dst[row + l31]      = o0[r] * inv;
            dst[row + 32 + l31] = o1[r] * inv;
        }
    }
}

// ---------------------------------------------------------------------------
// Combine the two KV-halves: O = (O1*a1 + O2*a2) / (l1*a1 + l2*a2)
// ---------------------------------------------------------------------------
__global__ __launch_bounds__(256) void combine_kernel(
    float* __restrict__ O1, const float* __restrict__ O2,
    const float* __restrict__ ML)
{
    const long flat = (long)blockIdx.x * 256 + threadIdx.x;  // 2^20 total
    const int  dg = (int)(flat & 15);
    const long q  = (flat >> 4) & (S_LEN - 1);
    const int  bh = (int)(flat >> 16);
    const float2 ml1 = ((const float2*)ML)[(long)(0 * NBH + bh) * S_LEN + q];
    const float2 ml2 = ((const float2*)ML)[(long)(1 * NBH + bh) * S_LEN + q];
    const float m  = fmaxf(ml1.x, ml2.x);
    const float a1 = __builtin_amdgcn_exp2f(ml1.x - m);
    const float a2 = __builtin_amdgcn_exp2f(ml2.x - m);
    const float inv = __builtin_amdgcn_rcpf(ml1.y * a1 + ml2.y * a2);
    const long idx = ((long)bh * S_LEN + q) * DHEAD + dg * 4;
    float4 x1 = *(const float4*)&O1[idx];
    float4 x2 = *(const float4*)&O2[idx];
    float4 r;
    r.x = (x1.x * a1 + x2.x * a2) * inv;
    r.y = (x1.y * a1 + x2.y * a2) * inv;
    r.z = (x1.z * a1 + x2.z * a2) * inv;
    r.w = (x1.w * a1 + x2.w * a2) * inv;
    *(float4*)&O1[idx] = r;
}

// ---------------------------------------------------------------------------
// Fallback (tiny ws): verified fp32-input kernel, verbatim.
// ---------------------------------------------------------------------------
__global__ __launch_bounds__(256, 2) void attn_kernel_fb(
    const float* __restrict__ Q, const float* __restrict__ K,
    const float* __restrict__ V, const int* __restrict__ dk,
    const float* __restrict__ mask, const int* __restrict__ maskflag,
    float* __restrict__ O)
{
    const int qt   = blockIdx.x;
    const int bh   = blockIdx.y;
    const int tid  = threadIdx.x;
    const int wave = tid >> 6;
    const int lane = tid & 63;
    const int l15  = lane & 15;
    const int quad = lane >> 4;

    const long base = (long)bh * S_LEN * DHEAD;
    const float* Qh = Q + base;
    const float* Kh = K + base;
    const float* Vh = V + base;
    float*       Oh = O + base;

    const int q0 = qt * BQ + wave * 32;
    const float csq  = rsqrtf((float)dk[0]) * 1.44269504088896f;
    const float mfac = -1e9f * 1.44269504088896f;
    const bool use_mask = (maskflag[0] != 0);

    __shared__ __align__(16) _Float16 Kt[2][BK][KPAD];
    __shared__ __align__(16) _Float16 Vt[2][DHEAD * KPAD];
    __shared__ __align__(16) _Float16 Pw[4][32][KPAD];

    half8 qf[2][2];
    #pragma unroll
    for (int f = 0; f < 2; ++f) {
        #pragma unroll
        for (int kc = 0; kc < 2; ++kc) {
            const float4* src = (const float4*)(Qh + (long)(q0 + f*16 + l15) * DHEAD + kc*32 + quad*8);
            float4 a = src[0], b = src[1];
            union { pk16x2 p[4]; half8 h; } u;
            u.p[0] = __builtin_amdgcn_cvt_pkrtz(a.x*csq, a.y*csq);
            u.p[1] = __builtin_amdgcn_cvt_pkrtz(a.z*csq, a.w*csq);
            u.p[2] = __builtin_amdgcn_cvt_pkrtz(b.x*csq, b.y*csq);
            u.p[3] = __builtin_amdgcn_cvt_pkrtz(b.z*csq, b.w*csq);
            qf[f][kc] = u.h;
        }
    }

    const int kr  = tid >> 2;
    const int ks  = tid & 3;
    const int vrp = tid >> 3;
    const int vdq = tid & 7;
    const float* Kb = Kh + (long)kr * DHEAD + ks * 16;
    const float* Vb = Vh + (long)(2 * vrp) * DHEAD + vdq * 8;
    const int vcol = (((vrp >> 2) ^ vdq) << 3) + ((2 * vrp) & 7);
    const int vd0  = vdq * 8;

    float4 kf[4], vf[4];
    auto load_tile = [&](int kt) {
        const float4* kp  = (const float4*)(Kb + (long)kt * BK * DHEAD);
        kf[0] = kp[0]; kf[1] = kp[1]; kf[2] = kp[2]; kf[3] = kp[3];
        const float4* vp0 = (const float4*)(Vb + (long)kt * BK * DHEAD);
        const float4* vp1 = (const float4*)(Vb + (long)kt * BK * DHEAD + DHEAD);
        vf[0] = vp0[0]; vf[1] = vp0[1]; vf[2] = vp1[0]; vf[3] = vp1[1];
    };
    auto store_tile = [&](int b) {
        union { pk16x2 p[4]; half8 h; } u0, u1;
        u0.p[0] = __builtin_amdgcn_cvt_pkrtz(kf[0].x, kf[0].y);
        u0.p[1] = __builtin_amdgcn_cvt_pkrtz(kf[0].z, kf[0].w);
        u0.p[2] = __builtin_amdgcn_cvt_pkrtz(kf[1].x, kf[1].y);
        u0.p[3] = __builtin_amdgcn_cvt_pkrtz(kf[1].z, kf[1].w);
        u1.p[0] = __builtin_amdgcn_cvt_pkrtz(kf[2].x, kf[2].y);
        u1.p[1] = __builtin_amdgcn_cvt_pkrtz(kf[2].z, kf[2].w);
        u1.p[2] = __builtin_amdgcn_cvt_pkrtz(kf[3].x, kf[3].y);
        u1.p[3] = __builtin_amdgcn_cvt_pkrtz(kf[3].z, kf[3].w);
        *(half8*)&Kt[b][kr][ks*16]     = u0.h;
        *(half8*)&Kt[b][kr][ks*16 + 8] = u1.h;
        _Float16* vt = &Vt[b][0];
        *(pk16x2*)&vt[(vd0+0)*KPAD + vcol] = __builtin_amdgcn_cvt_pkrtz(vf[0].x, vf[2].x);
        *(pk16x2*)&vt[(vd0+1)*KPAD + vcol] = __builtin_amdgcn_cvt_pkrtz(vf[0].y, vf[2].y);
        *(pk16x2*)&vt[(vd0+2)*KPAD + vcol] = __builtin_amdgcn_cvt_pkrtz(vf[0].z, vf[2].z);
        *(pk16x2*)&vt[(vd0+3)*KPAD + vcol] = __builtin_amdgcn_cvt_pkrtz(vf[0].w, vf[2].w);
        *(pk16x2*)&vt[(vd0+4)*KPAD + vcol] = __builtin_amdgcn_cvt_pkrtz(vf[1].x, vf[3].x);
        *(pk16x2*)&vt[(vd0+5)*KPAD + vcol] = __builtin_amdgcn_cvt_pkrtz(vf[1].y, vf[3].y);
        *(pk16x2*)&vt[(vd0+6)*KPAD + vcol] = __builtin_amdgcn_cvt_pkrtz(vf[1].z, vf[3].z);
        *(pk16x2*)&vt[(vd0+7)*KPAD + vcol] = __builtin_amdgcn_cvt_pkrtz(vf[1].w, vf[3].w);
    };

    f32x4 o[2][4];
    #pragma unroll
    for (int f = 0; f < 2; ++f)
        #pragma unroll
        for (int dt = 0; dt < 4; ++dt) o[f][dt] = (f32x4){0.f, 0.f, 0.f, 0.f};
    float m_i[2] = {-INFINITY, -INFINITY};
    float l_i[2] = {0.0f, 0.0f};

    load_tile(0);
    store_tile(0);
    __syncthreads();

    for (int kt = 0; kt < NT; ++kt) {
        const int b = kt & 1;
        if (kt + 1 < NT) load_tile(kt + 1);

        f32x4 st[2][4];
        #pragma unroll
        for (int f = 0; f < 2; ++f)
            #pragma unroll
            for (int nt = 0; nt < 4; ++nt) st[f][nt] = (f32x4){0.f,0.f,0.f,0.f};
        #pragma unroll
        for (int nt = 0; nt < 4; ++nt) {
            #pragma unroll
            for (int kc = 0; kc < 2; ++kc) {
                half8 af = *(const half8*)&Kt[b][nt*16 + l15][kc*32 + quad*8];
                st[0][nt] = __builtin_amdgcn_mfma_f32_16x16x32_f16(af, qf[0][kc], st[0][nt], 0, 0, 0);
                st[1][nt] = __builtin_amdgcn_mfma_f32_16x16x32_f16(af, qf[1][kc], st[1][nt], 0, 0, 0);
            }
        }

        if (use_mask) {
            #pragma unroll
            for (int f = 0; f < 2; ++f) {
                const long mrow = (long)(q0 + f*16 + l15) * S_LEN + kt*BK;
                #pragma unroll
                for (int nt = 0; nt < 4; ++nt)
                    #pragma unroll
                    for (int r = 0; r < 4; ++r)
                        st[f][nt][r] += mfac * mask[mrow + nt*16 + quad*4 + r];
            }
        }

        float alpha[2];
        #pragma unroll
        for (int f = 0; f < 2; ++f) {
            float mx = fmaxf(fmaxf(fmaxf(st[f][0][0], st[f][0][1]), fmaxf(st[f][0][2], st[f][0][3])),
                             fmaxf(fmaxf(st[f][1][0], st[f][1][1]), fmaxf(st[f][1][2], st[f][1][3])));
            float mx2 = fmaxf(fmaxf(fmaxf(st[f][2][0], st[f][2][1]), fmaxf(st[f][2][2], st[f][2][3])),
                              fmaxf(fmaxf(st[f][3][0], st[f][3][1]), fmaxf(st[f][3][2], st[f][3][3])));
            mx = fmaxf(mx, mx2);
            mx = fmaxf(mx, __shfl_xor(mx, 16, 64));
            mx = fmaxf(mx, __shfl_xor(mx, 32, 64));
            float mnew = fmaxf(m_i[f], mx);
            float rsum = 0.0f;
            #pragma unroll
            for (int nt = 0; nt < 4; ++nt) {
                #pragma unroll
                for (int r = 0; r < 4; ++r) {
                    float p = __builtin_amdgcn_exp2f(st[f][nt][r] - mnew);
                    st[f][nt][r] = p;
                    rsum += p;
                }
            }
            rsum += __shfl_xor(rsum, 16, 64);
            rsum += __shfl_xor(rsum, 32, 64);
            alpha[f] = __builtin_amdgcn_exp2f(m_i[f] - mnew);
            l_i[f] = alpha[f] * l_i[f] + rsum;
            m_i[f] = mnew;
        }

        #pragma unroll
        for (int f = 0; f < 2; ++f)
            #pragma unroll
            for (int r = 0; r < 4; ++r) {
                float a_r = __shfl(alpha[f], quad*4 + r, 64);
                #pragma unroll
                for (int dt = 0; dt < 4; ++dt) o[f][dt][r] *= a_r;
            }

        #pragma unroll
        for (int f = 0; f < 2; ++f)
            #pragma unroll
            for (int nt = 0; nt < 4; ++nt) {
                union { pk16x2 p[2]; half4v h; } up;
                up.p[0] = __builtin_amdgcn_cvt_pkrtz(st[f][nt][0], st[f][nt][1]);
                up.p[1] = __builtin_amdgcn_cvt_pkrtz(st[f][nt][2], st[f][nt][3]);
                *(half4v*)&Pw[wave][f*16 + l15][nt*16 + quad*4] = up.h;
            }

        #pragma unroll
        for (int kc2 = 0; kc2 < 2; ++kc2) {
            half8 pa0 = *(const half8*)&Pw[wave][l15][kc2*32 + quad*8];
            half8 pa1 = *(const half8*)&Pw[wave][16 + l15][kc2*32 + quad*8];
            #pragma unroll
            for (int dt = 0; dt < 4; ++dt) {
                const int row = dt*16 + l15;
                const int pb  = (4*kc2 + quad) ^ (row >> 3);
                half8 vb = *(const half8*)&Vt[b][row*KPAD + pb*8];
                o[0][dt] = __builtin_amdgcn_mfma_f32_16x16x32_f16(pa0, vb, o[0][dt], 0, 0, 0);
                o[1][dt] = __builtin_amdgcn_mfma_f32_16x16x32_f16(pa1, vb, o[1][dt], 0, 0, 0);
            }
        }

        if (kt + 1 < NT) {
            store_tile((kt + 1) & 1);
            __syncthreads();
        }
    }

    #pragma unroll
    for (int f = 0; f < 2; ++f) {
        #pragma unroll
        for (int r = 0; r < 4; ++r) {
            float lq = __shfl(l_i[f], quad*4 + r, 64);
            float linv = __builtin_amdgcn_rcpf(lq);
            const long row = (long)(q0 + f*16 + quad*4 + r) * DHEAD;
            #pragma unroll
            for (int dt = 0; dt < 4; ++dt)
                Oh[row + dt*16 + l15] = o[f][dt][r] * linv;
        }
    }
}

extern "C" void kernel_launch(void* const* d_in, const int* in_sizes, int n_in,
                              void* d_out, int out_size, void* d_ws, size_t ws_size,
                              hipStream_t stream) {
    const float* Q    = (const float*)d_in[0];
    const float* K    = (const float*)d_in[1];
    const float* V    = (const float*)d_in[2];
    const int*   dk   = (const int*)d_in[3];
    const float* mask = (const float*)d_in[4];
    float* out = (float*)d_out;
    int* flag = (int*)d_ws;

    (void)hipMemsetAsync(flag, 0, sizeof(int), stream);

    const size_t KV_BYTES = 2 * WS_KV_HALFS * sizeof(_Float16);               // 16.78 MB
    const size_t O2_BYTES = (size_t)NBH * S_LEN * DHEAD * sizeof(float);      // 16.78 MB
    const size_t ML_BYTES = 2ull * NBH * S_LEN * 2 * sizeof(float);           //  1.05 MB
    const size_t NEED_BASE  = 256 + KV_BYTES;
    const size_t NEED_SPLIT = NEED_BASE + O2_BYTES + ML_BYTES;

    if (ws_size >= NEED_BASE) {
        _Float16* wsK = (_Float16*)((char*)d_ws + 256);
        _Float16* wsV = wsK + WS_KV_HALFS;
        conv_kernel<<<dim3(NBH * NT, 3), 256, 0, stream>>>(K, V, mask, wsK, wsV, flag);
        if (ws_size >= NEED_SPLIT) {
            float* O2 = (float*)((char*)d_ws + 256 + KV_BYTES);
            float* ML = (float*)((char*)d_ws + 256 + KV_BYTES + O2_BYTES);
            attn32_kernel<2><<<1024, 256, 0, stream>>>(Q, wsK, wsV, dk, mask, flag, out, O2, ML);
            combine_kernel<<<4096, 256, 0, stream>>>(out, O2, ML);
        } else {
            attn32_kernel<1><<<512, 256, 0, stream>>>(Q, wsK, wsV, dk, mask, flag, out, nullptr, nullptr);
        }
    } else {
        mask_flag_kernel<<<2048, 256, 0, stream>>>((const float4*)mask, flag);
        dim3 grid(S_LEN / BQ, NBH);
        attn_kernel_fb<<<grid, 256, 0, stream>>>(Q, K, V, dk, mask, flag, out);
    }
}